// Round 6
// baseline (122.354 us; speedup 1.0000x reference)
//
#include <hip/hip_runtime.h>

// Fused persistent kernel — single-trip incremental poll-consume.
// 14-step recurrence, N=1680:
//   temp = J @ r_{t-1};  U = temp + Iext;  sq = (0.2U)^2
//   recSum = 0.005*sum(sq);  r_t = sq/recSum
// Invariant: carry unnormalized r̃_t = sq_t;  s_t = 0.005*sum(r̃_t);
//   J @ r_{t-1} = (J @ r̃_{t-1}) / s_{t-1}.
//
// Protocol (data IS the barrier): 14 per-step buffers of 420 quads,
// sentinel-filled 0xBF (-1.498f < 0) per launch; a quad is valid iff all
// 4 elems >= 0 (sq is a square; every element checked -> tear-safe).
// Round-6: every wave polls its own 7 quads and CONSUMES each quad the
// moment it turns valid (FMA into acc, add into psum, clear pend bit) —
// detect + load + dot collapse into ONE memory round trip per step, and
// the final pass only does the last quad's FMAs. s_sleep(1) backoff
// between passes bounds poll traffic. J row fragments are loaded via
// volatile-asm defs: asm outputs can't be rematerialized, so J is truly
// VGPR-resident for the whole kernel (verify: VGPR_Count ~200, was 104).

typedef float f32x4 __attribute__((ext_vector_type(4)));

#define N      1680
#define NV4    420          // N/4
#define NSTEP  14
#define GBLK   105          // blocks; 105*16 = 1680 rows
#define RPB    16           // rows per block
#define RPW    4            // rows per wave

// 7 plain cached loads as asm defs (J prologue — one-time, wants caching).
__device__ __forceinline__ void jload7(
    const f32x4* p0, const f32x4* p1, const f32x4* p2, const f32x4* p3,
    const f32x4* p4, const f32x4* p5, const f32x4* p6,
    f32x4& v0, f32x4& v1, f32x4& v2, f32x4& v3,
    f32x4& v4, f32x4& v5, f32x4& v6)
{
    asm volatile(
        "global_load_dwordx4 %0, %7, off\n\t"
        "global_load_dwordx4 %1, %8, off\n\t"
        "global_load_dwordx4 %2, %9, off\n\t"
        "global_load_dwordx4 %3, %10, off\n\t"
        "global_load_dwordx4 %4, %11, off\n\t"
        "global_load_dwordx4 %5, %12, off\n\t"
        "global_load_dwordx4 %6, %13, off\n\t"
        "s_waitcnt vmcnt(0)"
        : "=&v"(v0), "=&v"(v1), "=&v"(v2), "=&v"(v3),
          "=&v"(v4), "=&v"(v5), "=&v"(v6)
        : "v"(p0), "v"(p1), "v"(p2), "v"(p3), "v"(p4), "v"(p5), "v"(p6));
}

// 7 LLC-coherent loads (bypass L1/L2), one vmcnt drain.
__device__ __forceinline__ void load7_llc(
    const f32x4* p0, const f32x4* p1, const f32x4* p2, const f32x4* p3,
    const f32x4* p4, const f32x4* p5, const f32x4* p6,
    f32x4& v0, f32x4& v1, f32x4& v2, f32x4& v3,
    f32x4& v4, f32x4& v5, f32x4& v6)
{
    asm volatile(
        "global_load_dwordx4 %0, %7, off sc0 sc1\n\t"
        "global_load_dwordx4 %1, %8, off sc0 sc1\n\t"
        "global_load_dwordx4 %2, %9, off sc0 sc1\n\t"
        "global_load_dwordx4 %3, %10, off sc0 sc1\n\t"
        "global_load_dwordx4 %4, %11, off sc0 sc1\n\t"
        "global_load_dwordx4 %5, %12, off sc0 sc1\n\t"
        "global_load_dwordx4 %6, %13, off sc0 sc1\n\t"
        "s_waitcnt vmcnt(0)"
        : "=&v"(v0), "=&v"(v1), "=&v"(v2), "=&v"(v3),
          "=&v"(v4), "=&v"(v5), "=&v"(v6)
        : "v"(p0), "v"(p1), "v"(p2), "v"(p3), "v"(p4), "v"(p5), "v"(p6)
        : "memory");
}

__device__ __forceinline__ void llc_store4(f32x4* p, f32x4 v) {
    asm volatile("global_store_dwordx4 %0, %1, off sc0 sc1"
                 :: "v"(p), "v"(v) : "memory");
}

__global__ __launch_bounds__(256, 1) void fused_recur(
    const float* __restrict__ J,
    const float* __restrict__ net_in,     // [0,N): Iext ; [N,2N): r0
    float* __restrict__ out,              // U_13 (N) | recSum_13 (1) | r_13 (N)
    float* __restrict__ ws)               // 14 * 420 f32x4, sentinel-filled
{
    f32x4* bufs = (f32x4*)ws;

    const int tid  = threadIdx.x;
    const int lane = tid & 63;
    const int wave = tid >> 6;
    const int row0 = (int)blockIdx.x * RPB + wave * RPW;

    // lanes >= 36 have no slot 6 (only 420 quads); their q6 addr clamps to
    // quad 0 (harmless) and pend bit 6 starts cleared.
    const unsigned pend0 = (lane < 36) ? 0x7Fu : 0x3Fu;

    // ---- J rows -> VGPRs via asm defs (cannot be rematerialized) ----
    f32x4 Jr[RPW][7];
    #pragma unroll
    for (int m = 0; m < RPW; ++m) {
        const f32x4* jb = (const f32x4*)(J + (size_t)(row0 + m) * N);
        jload7(jb + lane,       jb + lane + 64,  jb + lane + 128,
               jb + lane + 192, jb + lane + 256, jb + lane + 320,
               (lane < 36) ? (jb + lane + 384) : jb,
               Jr[m][0], Jr[m][1], Jr[m][2], Jr[m][3],
               Jr[m][4], Jr[m][5], Jr[m][6]);
    }

    float iext[RPW];
    #pragma unroll
    for (int m = 0; m < RPW; ++m) iext[m] = net_in[row0 + m];

    float Uv[RPW], Qv[RPW];

    #pragma unroll 1
    for (int t = 0; t < NSTEP; ++t) {
        f32x4 acc[RPW];
        #pragma unroll
        for (int m = 0; m < RPW; ++m) acc[m] = (f32x4)0.f;
        float psum = 0.0f;

        if (t == 0) {
            const f32x4* r0 = (const f32x4*)(net_in + N);
            #pragma unroll
            for (int k = 0; k < 7; ++k) {
                const int idx = lane + 64 * k;
                const f32x4 q = (idx < NV4) ? r0[idx] : (f32x4)0.f;
                #pragma unroll
                for (int m = 0; m < RPW; ++m) {
                    acc[m][0] += Jr[m][k][0] * q[0];
                    acc[m][1] += Jr[m][k][1] * q[1];
                    acc[m][2] += Jr[m][k][2] * q[2];
                    acc[m][3] += Jr[m][k][3] * q[3];
                }
            }
        } else {
            const f32x4* base = bufs + (size_t)(t - 1) * NV4;
            const f32x4* q0 = base + lane;
            const f32x4* q1 = base + lane + 64;
            const f32x4* q2 = base + lane + 128;
            const f32x4* q3 = base + lane + 192;
            const f32x4* q4 = base + lane + 256;
            const f32x4* q5 = base + lane + 320;
            const f32x4* q6 = (lane < 36) ? (base + lane + 384) : base;

            unsigned pend = pend0;
            for (;;) {
                f32x4 rv[7];
                load7_llc(q0, q1, q2, q3, q4, q5, q6,
                          rv[0], rv[1], rv[2], rv[3], rv[4], rv[5], rv[6]);
                #pragma unroll
                for (int k = 0; k < 7; ++k) {
                    if ((pend >> k) & 1u) {
                        const f32x4 q = rv[k];
                        const float mn = fminf(fminf(q[0], q[1]),
                                               fminf(q[2], q[3]));
                        if (mn >= 0.0f) {       // newly valid: consume now
                            #pragma unroll
                            for (int m = 0; m < RPW; ++m) {
                                acc[m][0] += Jr[m][k][0] * q[0];
                                acc[m][1] += Jr[m][k][1] * q[1];
                                acc[m][2] += Jr[m][k][2] * q[2];
                                acc[m][3] += Jr[m][k][3] * q[3];
                            }
                            psum += (q[0] + q[1]) + (q[2] + q[3]);
                            pend &= ~(1u << k);
                        }
                    }
                }
                if (!__any((int)pend)) break;   // wave-uniform exit
                __builtin_amdgcn_s_sleep(1);    // backoff: bound poll traffic
            }
        }

        // fold vector accumulators, 5-value butterfly reduce
        float red[5];
        #pragma unroll
        for (int m = 0; m < RPW; ++m)
            red[m] = (acc[m][0] + acc[m][1]) + (acc[m][2] + acc[m][3]);
        red[4] = psum;
        #pragma unroll
        for (int off = 32; off; off >>= 1) {
            #pragma unroll
            for (int i = 0; i < 5; ++i) red[i] += __shfl_xor(red[i], off, 64);
        }
        const float inv = (t == 0) ? 1.0f : 1.0f / (0.005f * red[4]);

        #pragma unroll
        for (int m = 0; m < RPW; ++m) {
            const float U  = red[m] * inv + iext[m];    // ALPHA=BETA=1
            const float u2 = 0.2f * U;
            Uv[m] = U;
            Qv[m] = u2 * u2;                            // sq >= 0 always
        }

        // publish this wave's 4 rows: the store IS the signal
        if (lane == 0) {
            f32x4 pub = { Qv[0], Qv[1], Qv[2], Qv[3] };
            llc_store4(bufs + (size_t)t * NV4 + (row0 >> 2), pub);
        }
    }

    // ---- finish: incremental psum-only poll of buf[13] -> s13 ----
    float s13;
    {
        const f32x4* base = bufs + (size_t)(NSTEP - 1) * NV4;
        const f32x4* q0 = base + lane;
        const f32x4* q1 = base + lane + 64;
        const f32x4* q2 = base + lane + 128;
        const f32x4* q3 = base + lane + 192;
        const f32x4* q4 = base + lane + 256;
        const f32x4* q5 = base + lane + 320;
        const f32x4* q6 = (lane < 36) ? (base + lane + 384) : base;

        unsigned pend = pend0;
        float psum = 0.0f;
        for (;;) {
            f32x4 rv[7];
            load7_llc(q0, q1, q2, q3, q4, q5, q6,
                      rv[0], rv[1], rv[2], rv[3], rv[4], rv[5], rv[6]);
            #pragma unroll
            for (int k = 0; k < 7; ++k) {
                if ((pend >> k) & 1u) {
                    const f32x4 q = rv[k];
                    const float mn = fminf(fminf(q[0], q[1]),
                                           fminf(q[2], q[3]));
                    if (mn >= 0.0f) {
                        psum += (q[0] + q[1]) + (q[2] + q[3]);
                        pend &= ~(1u << k);
                    }
                }
            }
            if (!__any((int)pend)) break;
            __builtin_amdgcn_s_sleep(1);
        }
        #pragma unroll
        for (int off = 32; off; off >>= 1) psum += __shfl_xor(psum, off, 64);
        s13 = 0.005f * psum;
    }

    if (lane == 0) {
        f32x4 u4 = { Uv[0], Uv[1], Uv[2], Uv[3] };
        *(f32x4*)(out + row0) = u4;                     // U_13 (16B aligned)
    }
    if (lane < RPW) {                                   // r_13 (offset N+1: scalar)
        const float q = (lane == 0) ? Qv[0] : (lane == 1) ? Qv[1]
                       : (lane == 2) ? Qv[2] : Qv[3];
        out[N + 1 + row0 + lane] = q / s13;
    }
    if (blockIdx.x == 0 && tid == 0) out[N] = s13;      // recSum_13
}

extern "C" void kernel_launch(void* const* d_in, const int* in_sizes, int n_in,
                              void* d_out, int out_size, void* d_ws, size_t ws_size,
                              hipStream_t stream) {
    const float* net_in = (const float*)d_in[0];   // 2N: Iext | r0
    const float* J      = (const float*)d_in[1];   // N x N row-major
    // Sentinel-fill all 14 step buffers: every byte 0xBF -> -1.498f (< 0).
    hipMemsetAsync(d_ws, 0xBF, (size_t)NSTEP * NV4 * sizeof(f32x4), stream);
    fused_recur<<<GBLK, 256, 0, stream>>>(J, net_in, (float*)d_out, (float*)d_ws);
}

// Round 7
// 111.274 us; speedup vs baseline: 1.0996x; 1.0996x over previous
//
#include <hip/hip_runtime.h>

// Fused persistent kernel — one poller per block, incremental LDS fan-out,
// J prefetch hidden under the spin.
// 14-step recurrence, N=1680:
//   temp = J @ r_{t-1};  U = temp + Iext;  sq = (0.2U)^2
//   recSum = 0.005*sum(sq);  r_t = sq/recSum
// Invariant: carry unnormalized r̃_t = sq_t;  s_t = 0.005*sum(r̃_t);
//   J @ r_{t-1} = (J @ r̃_{t-1}) / s_{t-1}.
//
// Protocol (data IS the barrier): 14 per-step buffers of 420 quads in ws,
// sentinel-filled 0xBF (-1.498f < 0) per launch; a quad is valid iff all
// 4 elems >= 0 (sq is a square; every element checked -> tear-safe).
//
// Round-7 structure (why): rounds 3-6 showed 105 pollers beat 420 (LLC
// poll-traffic contention: 9.6 vs 2.4 TB/s), LDS handoff beats per-wave
// LLC re-load (no 2.8MB sc1 burst), and J is NOT register-resident
// (VGPR=100 < 112) so its per-step L2 re-stream must be hidden. So:
//   wave 0: poll own 7 quads; ds_write each quad AS IT VALIDATES; on
//           all-valid (wave-uniform) release-store LDS flag. One LLC trip.
//   waves 1-3: issue 28 J loads (asm defs, no waitcnt) -> spin on LDS
//           flag (lgkm-only, J loads stay in flight) -> vmcnt(0) +
//           sched_barrier -> ds_read data -> FMA.
// No __syncthreads in the loop. LDS parity double-buffer is safe by
// induction: wave0 can't reach step t+2's writes before every wave
// published step t+1, which requires their step-t LDS reads done.

typedef float f32x4 __attribute__((ext_vector_type(4)));

#define N      1680
#define NV4    420          // N/4
#define NSTEP  14
#define GBLK   105          // blocks; 105*16 = 1680 rows
#define RPB    16           // rows per block
#define RPW    4            // rows per wave

// Issue 7 cached loads as asm defs, NO waitcnt (prefetch; drain later).
__device__ __forceinline__ void jload7_issue(
    const f32x4* p0, const f32x4* p1, const f32x4* p2, const f32x4* p3,
    const f32x4* p4, const f32x4* p5, const f32x4* p6,
    f32x4& v0, f32x4& v1, f32x4& v2, f32x4& v3,
    f32x4& v4, f32x4& v5, f32x4& v6)
{
    asm volatile(
        "global_load_dwordx4 %0, %7, off\n\t"
        "global_load_dwordx4 %1, %8, off\n\t"
        "global_load_dwordx4 %2, %9, off\n\t"
        "global_load_dwordx4 %3, %10, off\n\t"
        "global_load_dwordx4 %4, %11, off\n\t"
        "global_load_dwordx4 %5, %12, off\n\t"
        "global_load_dwordx4 %6, %13, off"
        : "=&v"(v0), "=&v"(v1), "=&v"(v2), "=&v"(v3),
          "=&v"(v4), "=&v"(v5), "=&v"(v6)
        : "v"(p0), "v"(p1), "v"(p2), "v"(p3), "v"(p4), "v"(p5), "v"(p6));
}

// Drain all vmem; fence the scheduler so uses can't hoist above (rule #18).
__device__ __forceinline__ void vm_wait0() {
    asm volatile("s_waitcnt vmcnt(0)" ::: "memory");
    __builtin_amdgcn_sched_barrier(0);
}

// 7 LLC-coherent loads (bypass L1/L2), one vmcnt drain.
__device__ __forceinline__ void load7_llc(
    const f32x4* p0, const f32x4* p1, const f32x4* p2, const f32x4* p3,
    const f32x4* p4, const f32x4* p5, const f32x4* p6,
    f32x4& v0, f32x4& v1, f32x4& v2, f32x4& v3,
    f32x4& v4, f32x4& v5, f32x4& v6)
{
    asm volatile(
        "global_load_dwordx4 %0, %7, off sc0 sc1\n\t"
        "global_load_dwordx4 %1, %8, off sc0 sc1\n\t"
        "global_load_dwordx4 %2, %9, off sc0 sc1\n\t"
        "global_load_dwordx4 %3, %10, off sc0 sc1\n\t"
        "global_load_dwordx4 %4, %11, off sc0 sc1\n\t"
        "global_load_dwordx4 %5, %12, off sc0 sc1\n\t"
        "global_load_dwordx4 %6, %13, off sc0 sc1\n\t"
        "s_waitcnt vmcnt(0)"
        : "=&v"(v0), "=&v"(v1), "=&v"(v2), "=&v"(v3),
          "=&v"(v4), "=&v"(v5), "=&v"(v6)
        : "v"(p0), "v"(p1), "v"(p2), "v"(p3), "v"(p4), "v"(p5), "v"(p6)
        : "memory");
}

__device__ __forceinline__ void llc_store4(f32x4* p, f32x4 v) {
    asm volatile("global_store_dwordx4 %0, %1, off sc0 sc1"
                 :: "v"(p), "v"(v) : "memory");
}

__global__ __launch_bounds__(256, 1) void fused_recur(
    const float* __restrict__ J,
    const float* __restrict__ net_in,     // [0,N): Iext ; [N,2N): r0
    float* __restrict__ out,              // U_13 (N) | recSum_13 (1) | r_13 (N)
    float* __restrict__ ws)               // 14 * 420 f32x4, sentinel-filled
{
    __shared__ f32x4 lds_r[2][NV4];       // parity double-buffer of r̃
    __shared__ float lds_flag[16];        // [t-1]: 1.0 = step t-1 in LDS; [15]: s13

    f32x4* bufs = (f32x4*)ws;

    const int tid  = threadIdx.x;
    const int lane = tid & 63;
    const int wave = tid >> 6;
    const int row0 = (int)blockIdx.x * RPB + wave * RPW;

    // lanes >= 36 have no slot 6 (only 420 quads); q6 addr clamps to quad 0.
    const unsigned pend0 = (lane < 36) ? 0x7Fu : 0x3Fu;

    if (tid < 16) lds_flag[tid] = 0.0f;
    __syncthreads();                      // one-time init (only block barrier)

    float iext[RPW];
    #pragma unroll
    for (int m = 0; m < RPW; ++m) iext[m] = net_in[row0 + m];

    const f32x4* jb[RPW];
    #pragma unroll
    for (int m = 0; m < RPW; ++m)
        jb[m] = (const f32x4*)(J + (size_t)(row0 + m) * N);

    float Uv[RPW], Qv[RPW];

    #pragma unroll 1
    for (int t = 0; t < NSTEP; ++t) {
        // -- issue this step's J loads (L2-cached); drained under the wait --
        f32x4 Jr[RPW][7];
        #pragma unroll
        for (int m = 0; m < RPW; ++m)
            jload7_issue(jb[m] + lane,       jb[m] + lane + 64,
                         jb[m] + lane + 128, jb[m] + lane + 192,
                         jb[m] + lane + 256, jb[m] + lane + 320,
                         (lane < 36) ? (jb[m] + lane + 384) : jb[m],
                         Jr[m][0], Jr[m][1], Jr[m][2], Jr[m][3],
                         Jr[m][4], Jr[m][5], Jr[m][6]);

        f32x4 rv[7];
        float psum = 0.0f;
        const int par = (t - 1) & 1;

        if (t == 0) {
            vm_wait0();
            const f32x4* r0 = (const f32x4*)(net_in + N);
            #pragma unroll
            for (int k = 0; k < 7; ++k) {
                const int idx = lane + 64 * k;
                rv[k] = (idx < NV4) ? r0[idx] : (f32x4)0.f;
            }
        } else if (wave == 0) {
            // ---- sole poller: incremental poll -> ds_write fan-out ----
            const f32x4* base = bufs + (size_t)(t - 1) * NV4;
            const f32x4* q0 = base + lane;
            const f32x4* q1 = base + lane + 64;
            const f32x4* q2 = base + lane + 128;
            const f32x4* q3 = base + lane + 192;
            const f32x4* q4 = base + lane + 256;
            const f32x4* q5 = base + lane + 320;
            const f32x4* q6 = (lane < 36) ? (base + lane + 384) : base;

            unsigned pend = pend0;
            #pragma unroll 1
            for (;;) {
                load7_llc(q0, q1, q2, q3, q4, q5, q6,   // vmcnt(0) drains J too
                          rv[0], rv[1], rv[2], rv[3], rv[4], rv[5], rv[6]);
                #pragma unroll
                for (int k = 0; k < 7; ++k) {
                    if ((pend >> k) & 1u) {
                        const f32x4 q = rv[k];
                        const float mn = fminf(fminf(q[0], q[1]),
                                               fminf(q[2], q[3]));
                        if (mn >= 0.0f) {       // valid: distribute NOW
                            lds_r[par][lane + 64 * k] = q;
                            pend &= ~(1u << k);
                        }
                    }
                }
                if (!__any(pend != 0u)) break;  // wave-uniform exit
            }
            if (lane == 0)      // release: lgkmcnt(0) covers all lanes' ds_writes
                __hip_atomic_store(&lds_flag[t - 1], 1.0f, __ATOMIC_RELEASE,
                                   __HIP_MEMORY_SCOPE_WORKGROUP);
            if (lane >= 36) rv[6] = (f32x4)0.f;
            #pragma unroll
            for (int k = 0; k < 7; ++k)
                psum += (rv[k][0] + rv[k][1]) + (rv[k][2] + rv[k][3]);
        } else {
            // ---- consumer: spin on LDS flag (J loads stay in flight) ----
            while (__hip_atomic_load(&lds_flag[t - 1], __ATOMIC_ACQUIRE,
                                     __HIP_MEMORY_SCOPE_WORKGROUP) == 0.0f) {}
            vm_wait0();                         // J landed during the spin
            #pragma unroll
            for (int k = 0; k < 7; ++k) {
                const int idx = lane + 64 * k;
                rv[k] = (idx < NV4) ? lds_r[par][idx] : (f32x4)0.f;
            }
            #pragma unroll
            for (int k = 0; k < 7; ++k)
                psum += (rv[k][0] + rv[k][1]) + (rv[k][2] + rv[k][3]);
        }

        // ---- 4 row-dots + psum, one 5-value butterfly ----
        f32x4 acc[RPW];
        #pragma unroll
        for (int m = 0; m < RPW; ++m) acc[m] = (f32x4)0.f;
        #pragma unroll
        for (int k = 0; k < 7; ++k) {
            #pragma unroll
            for (int m = 0; m < RPW; ++m) {
                acc[m][0] += Jr[m][k][0] * rv[k][0];
                acc[m][1] += Jr[m][k][1] * rv[k][1];
                acc[m][2] += Jr[m][k][2] * rv[k][2];
                acc[m][3] += Jr[m][k][3] * rv[k][3];
            }
        }
        float red[5];
        #pragma unroll
        for (int m = 0; m < RPW; ++m)
            red[m] = (acc[m][0] + acc[m][1]) + (acc[m][2] + acc[m][3]);
        red[4] = psum;
        #pragma unroll
        for (int off = 32; off; off >>= 1) {
            #pragma unroll
            for (int i = 0; i < 5; ++i) red[i] += __shfl_xor(red[i], off, 64);
        }
        const float inv = (t == 0) ? 1.0f : 1.0f / (0.005f * red[4]);

        #pragma unroll
        for (int m = 0; m < RPW; ++m) {
            const float U  = red[m] * inv + iext[m];    // ALPHA=BETA=1
            const float u2 = 0.2f * U;
            Uv[m] = U;
            Qv[m] = u2 * u2;                            // sq >= 0 always
        }

        // publish this wave's 4 rows: the store IS the signal
        if (lane == 0) {
            f32x4 pub = { Qv[0], Qv[1], Qv[2], Qv[3] };
            llc_store4(bufs + (size_t)t * NV4 + (row0 >> 2), pub);
        }
    }

    // ---- finish: s13 = 0.005 * sum(buf[13]); wave0 polls, shares via LDS ----
    float s13;
    if (wave == 0) {
        const f32x4* base = bufs + (size_t)(NSTEP - 1) * NV4;
        const f32x4* q0 = base + lane;
        const f32x4* q1 = base + lane + 64;
        const f32x4* q2 = base + lane + 128;
        const f32x4* q3 = base + lane + 192;
        const f32x4* q4 = base + lane + 256;
        const f32x4* q5 = base + lane + 320;
        const f32x4* q6 = (lane < 36) ? (base + lane + 384) : base;
        f32x4 rv[7];
        unsigned pend = pend0;
        float psum = 0.0f;
        #pragma unroll 1
        for (;;) {
            load7_llc(q0, q1, q2, q3, q4, q5, q6,
                      rv[0], rv[1], rv[2], rv[3], rv[4], rv[5], rv[6]);
            #pragma unroll
            for (int k = 0; k < 7; ++k) {
                if ((pend >> k) & 1u) {
                    const f32x4 q = rv[k];
                    const float mn = fminf(fminf(q[0], q[1]), fminf(q[2], q[3]));
                    if (mn >= 0.0f) {
                        psum += (q[0] + q[1]) + (q[2] + q[3]);
                        pend &= ~(1u << k);
                    }
                }
            }
            if (!__any(pend != 0u)) break;
        }
        #pragma unroll
        for (int off = 32; off; off >>= 1) psum += __shfl_xor(psum, off, 64);
        s13 = 0.005f * psum;                  // > 0 (sum of squares, random data)
        if (lane == 0)
            __hip_atomic_store(&lds_flag[15], s13, __ATOMIC_RELEASE,
                               __HIP_MEMORY_SCOPE_WORKGROUP);
    } else {
        float f;
        while ((f = __hip_atomic_load(&lds_flag[15], __ATOMIC_ACQUIRE,
                                      __HIP_MEMORY_SCOPE_WORKGROUP)) == 0.0f) {}
        s13 = f;
    }

    if (lane == 0) {
        f32x4 u4 = { Uv[0], Uv[1], Uv[2], Uv[3] };
        *(f32x4*)(out + row0) = u4;                     // U_13 (16B aligned)
    }
    if (lane < RPW) {                                   // r_13 (offset N+1: scalar)
        const float q = (lane == 0) ? Qv[0] : (lane == 1) ? Qv[1]
                       : (lane == 2) ? Qv[2] : Qv[3];
        out[N + 1 + row0 + lane] = q / s13;
    }
    if (blockIdx.x == 0 && tid == 0) out[N] = s13;      // recSum_13
}

extern "C" void kernel_launch(void* const* d_in, const int* in_sizes, int n_in,
                              void* d_out, int out_size, void* d_ws, size_t ws_size,
                              hipStream_t stream) {
    const float* net_in = (const float*)d_in[0];   // 2N: Iext | r0
    const float* J      = (const float*)d_in[1];   // N x N row-major
    // Sentinel-fill all 14 step buffers: every byte 0xBF -> -1.498f (< 0).
    hipMemsetAsync(d_ws, 0xBF, (size_t)NSTEP * NV4 * sizeof(f32x4), stream);
    fused_recur<<<GBLK, 256, 0, stream>>>(J, net_in, (float*)d_out, (float*)d_ws);
}